// Round 3
// baseline (155.483 us; speedup 1.0000x reference)
//
#include <hip/hip_runtime.h>
#include <hip/hip_bf16.h>
#include <math.h>

// Problem constants
#define B_SZ 8
#define LSEQ 4096
#define NDIM 256
#define HDIM 256
#define MROWS (B_SZ * LSEQ)     // 32768
#define CH 64                   // chunk length
#define NC (LSEQ / CH)          // 64 chunks per batch

#define BM 64                   // k_buscan m-tile (== chunk)
#define BN 128
#define BK 32
#define OBM 128                 // k_out m-tile (2 chunks)
#define SSTR 68                 // scan LDS col stride (halfs)

typedef _Float16 half8 __attribute__((ext_vector_type(8)));
typedef _Float16 half4 __attribute__((ext_vector_type(4)));
typedef float fx4 __attribute__((ext_vector_type(4)));

// ---------------------------------------------------------------------------
// k_prep: weights -> fp16 (gamma folded into B, Cim negated), Lambda re/im,
// and pow table P[i][n] = Lambda[n]^(i+1) for blocks < CH.  grid 256 x 256.
// ---------------------------------------------------------------------------
__global__ void k_prep(const float* __restrict__ Bre, const float* __restrict__ Bim,
                       const float* __restrict__ Cre, const float* __restrict__ Cim,
                       const float* __restrict__ nu_log, const float* __restrict__ th_log,
                       _Float16* __restrict__ BreH, _Float16* __restrict__ BimH,
                       _Float16* __restrict__ CreH, _Float16* __restrict__ CimNH,
                       float* __restrict__ lamRe, float* __restrict__ lamIm,
                       float* __restrict__ powRe, float* __restrict__ powIm) {
    int r = blockIdx.x;
    int t = threadIdx.x;
    float nu  = expf(nu_log[r]);
    float th  = expf(th_log[r]);
    float mod = expf(-nu);
    float g   = sqrtf(fmaxf(1.0f - mod * mod, 0.0f));
    if (t == 0) {
        lamRe[r] = mod * cosf(th);
        lamIm[r] = mod * sinf(th);
    }
    int i = r * 256 + t;
    BreH[i]  = (_Float16)(Bre[i] * g);
    BimH[i]  = (_Float16)(Bim[i] * g);
    CreH[i]  = (_Float16)Cre[i];
    CimNH[i] = (_Float16)(-Cim[i]);
    if (r < CH) {
        float nuN = expf(nu_log[t]);
        float thN = expf(th_log[t]);
        float k   = (float)(r + 1);
        float mo  = expf(-nuN * k);
        powRe[r * 256 + t] = mo * cosf(thN * k);
        powIm[r * 256 + t] = mo * sinf(thN * k);
    }
}

// ---------------------------------------------------------------------------
// k_buscan: fused  Bu = x @ B^T  GEMM  +  per-chunk local scan.
// (unchanged from verified round-2 version)
// ---------------------------------------------------------------------------
__launch_bounds__(256)
__global__ void k_buscan(const float* __restrict__ x,
                         const _Float16* __restrict__ BreH,
                         const _Float16* __restrict__ BimH,
                         const float* __restrict__ lamRe,
                         const float* __restrict__ lamIm,
                         _Float16* __restrict__ stReH,
                         _Float16* __restrict__ stImH,
                         float* __restrict__ finRe,
                         float* __restrict__ finIm) {
    __shared__ __align__(16) _Float16 smem[20480];

    const int tid  = threadIdx.x;
    const int lane = tid & 63;
    const int wave = tid >> 6;
    const int wr   = wave >> 1;
    const int wc   = wave & 1;
    const int m0   = blockIdx.x * BM;
    const int n0   = blockIdx.y * BN;

    const int ar = tid >> 2, ac = (tid & 3) * 8;
    const int aw = ar * 32 + (((tid & 3) ^ ((tid >> 3) & 3)) * 8);

    const int br = tid >> 1, g2 = tid & 1, bc = g2 * 16;
    const int fb = (br >> 1) & 3;
    const int bw0 = br * 32 + (((2 * g2)     ^ fb) * 8);
    const int bw1 = br * 32 + (((2 * g2 + 1) ^ fb) * 8);

    const int fRC   = lane & 15;
    const int rslot = (((lane >> 4) ^ (fRC >> 1)) & 3) * 8;

    fx4 accR[8], accI[8];
#pragma unroll
    for (int i = 0; i < 8; ++i) { accR[i] = (fx4)0.0f; accI[i] = (fx4)0.0f; }

    float4 xf0, xf1;
    half8 w0, w1, w2, w3;

#define LOAD_T(K0)                                                          \
    {                                                                       \
        const float* xp = x + (size_t)(m0 + ar) * HDIM + (K0) + ac;         \
        xf0 = *(const float4*)xp;                                           \
        xf1 = *(const float4*)(xp + 4);                                     \
        const _Float16* bp1 = BreH + (size_t)(n0 + br) * HDIM + (K0) + bc;  \
        const _Float16* bp2 = BimH + (size_t)(n0 + br) * HDIM + (K0) + bc;  \
        w0 = *(const half8*)bp1;  w1 = *(const half8*)(bp1 + 8);            \
        w2 = *(const half8*)bp2;  w3 = *(const half8*)(bp2 + 8);            \
    }
#define WRITE_T(PO)                                                         \
    {                                                                       \
        half8 hv;                                                           \
        hv[0]=(_Float16)xf0.x; hv[1]=(_Float16)xf0.y; hv[2]=(_Float16)xf0.z; hv[3]=(_Float16)xf0.w; \
        hv[4]=(_Float16)xf1.x; hv[5]=(_Float16)xf1.y; hv[6]=(_Float16)xf1.z; hv[7]=(_Float16)xf1.w; \
        *(half8*)&smem[(PO) + aw] = hv;                                     \
        *(half8*)&smem[(PO) + 2048 + bw0] = w0;                             \
        *(half8*)&smem[(PO) + 2048 + bw1] = w1;                             \
        *(half8*)&smem[(PO) + 6144 + bw0] = w2;                             \
        *(half8*)&smem[(PO) + 6144 + bw1] = w3;                             \
    }

    LOAD_T(0);
    WRITE_T(0);
    __syncthreads();

    int p = 0;
    for (int k0 = 0; k0 < HDIM; k0 += BK) {
        const int po = p * 10240;
        const int qo = (p ^ 1) * 10240;
        const bool nx = (k0 + BK) < HDIM;
        if (nx) LOAD_T(k0 + BK);
        half8 af[2], bf[4];
#pragma unroll
        for (int sm = 0; sm < 2; ++sm)
            af[sm] = *(const half8*)&smem[po + (wr * 32 + sm * 16 + fRC) * 32 + rslot];
#pragma unroll
        for (int sn = 0; sn < 4; ++sn)
            bf[sn] = *(const half8*)&smem[po + 2048 + (wc * 64 + sn * 16 + fRC) * 32 + rslot];
#pragma unroll
        for (int sm = 0; sm < 2; ++sm)
#pragma unroll
            for (int sn = 0; sn < 4; ++sn)
                accR[sm * 4 + sn] = __builtin_amdgcn_mfma_f32_16x16x32_f16(af[sm], bf[sn], accR[sm * 4 + sn], 0, 0, 0);
#pragma unroll
        for (int sn = 0; sn < 4; ++sn)
            bf[sn] = *(const half8*)&smem[po + 6144 + (wc * 64 + sn * 16 + fRC) * 32 + rslot];
#pragma unroll
        for (int sm = 0; sm < 2; ++sm)
#pragma unroll
            for (int sn = 0; sn < 4; ++sn)
                accI[sm * 4 + sn] = __builtin_amdgcn_mfma_f32_16x16x32_f16(af[sm], bf[sn], accI[sm * 4 + sn], 0, 0, 0);
        if (nx) WRITE_T(qo);
        __syncthreads();
        p ^= 1;
    }
#undef LOAD_T
#undef WRITE_T

    _Float16* SRe = smem;
    _Float16* SIm = smem + 8704;

    const int rBase = (lane >> 4) * 4;
#pragma unroll
    for (int sm = 0; sm < 2; ++sm)
#pragma unroll
        for (int sn = 0; sn < 4; ++sn) {
            int col = wc * 64 + sn * 16 + fRC;
            int row = wr * 32 + sm * 16 + rBase;
            half4 h1, h2;
#pragma unroll
            for (int reg = 0; reg < 4; ++reg) {
                h1[reg] = (_Float16)accR[sm * 4 + sn][reg];
                h2[reg] = (_Float16)accI[sm * 4 + sn][reg];
            }
            *(half4*)&SRe[col * SSTR + row] = h1;
            *(half4*)&SIm[col * SSTR + row] = h2;
        }
    __syncthreads();

    if (tid < BN) {
        int col = tid;
        int n = n0 + col;
        float lr = lamRe[n], li = lamIm[n];
        _Float16* cR = &SRe[col * SSTR];
        _Float16* cI = &SIm[col * SSTR];
        float sr = 0.0f, si = 0.0f;
#pragma unroll 8
        for (int r = 0; r < CH; ++r) {
            float ur = (float)cR[r];
            float ui = (float)cI[r];
            float nr = fmaf(lr, sr, fmaf(-li, si, ur));
            float ni = fmaf(lr, si, fmaf(li, sr, ui));
            sr = nr; si = ni;
            cR[r] = (_Float16)sr;
            cI[r] = (_Float16)si;
        }
        int bb = blockIdx.x >> 6, cc = blockIdx.x & 63;
        size_t f = ((size_t)(bb * NC + cc)) * NDIM + n;
        finRe[f] = sr;
        finIm[f] = si;
    }
    __syncthreads();

    {
        int row = tid >> 2;
        int cb  = (tid & 3) * 8;
        size_t gbase = (size_t)(m0 + row) * NDIM + n0 + cb;
#pragma unroll
        for (int g = 0; g < 4; ++g) {
            half8 h1, h2;
#pragma unroll
            for (int e = 0; e < 8; ++e) {
                int col = cb + g * 32 + e;
                h1[e] = SRe[col * SSTR + row];
                h2[e] = SIm[col * SSTR + row];
            }
            *(half8*)(stReH + gbase + g * 32) = h1;
            *(half8*)(stImH + gbase + g * 32) = h2;
        }
    }
}

// ---------------------------------------------------------------------------
// k_carry: Kogge-Stone scan over the 64 chunk finals, chunks in lanes.
// (unchanged from verified round-2 version)
// ---------------------------------------------------------------------------
__launch_bounds__(256)
__global__ void k_carry(const float* __restrict__ lamRe,
                        const float* __restrict__ lamIm,
                        const float* __restrict__ finRe,
                        const float* __restrict__ finIm,
                        float* __restrict__ carRe,
                        float* __restrict__ carIm) {
    const int tid  = threadIdx.x;
    const int lane = tid & 63;
    const int wv   = tid >> 6;
    const int idx  = blockIdx.x * 4 + wv;
    const int b    = idx >> 8;
    const int n    = idx & 255;

    float plr = lamRe[n], pli = lamIm[n];
#pragma unroll
    for (int i = 0; i < 6; ++i) {
        float t = plr * plr - pli * pli;
        pli = 2.0f * plr * pli;
        plr = t;
    }

    size_t base = ((size_t)(b * NC + lane)) * NDIM + n;
    float vr = finRe[base];
    float vi = finIm[base];

#pragma unroll
    for (int d = 1; d < 64; d <<= 1) {
        float vpr = __shfl_up(vr, d);
        float vpi = __shfl_up(vi, d);
        float lpr = __shfl_up(plr, d);
        float lpi = __shfl_up(pli, d);
        if (lane >= d) {
            float nvr = fmaf(plr, vpr, fmaf(-pli, vpi, vr));
            float nvi = fmaf(plr, vpi, fmaf(pli, vpr, vi));
            vr = nvr; vi = nvi;
            float t = plr * lpr - pli * lpi;
            pli = fmaf(plr, lpi, pli * lpr);
            plr = t;
        }
    }

    float cr = __shfl_up(vr, 1);
    float ci = __shfl_up(vi, 1);
    if (lane == 0) { cr = 0.0f; ci = 0.0f; }
    carRe[base] = cr;
    carIm[base] = ci;
}

// ---------------------------------------------------------------------------
// k_out: y = s @ CreH^T + sIm @ CimNH^T + x*D, carry applied during A-staging:
// state[i] = local[i] + P[i]*carry  (P = Lambda^(i+1)).
// NEW: OBM=128 m-tile (2 chunks/block; powRow = row&63, chunk = m0/64+row/64).
// 4 waves, wave tile 64x64, 16 fragments, 32 MFMA per K-step per wave.
// Same verified swizzled-linear LDS layout; A staged like the C map.
// LDS 65536 B -> 2 blocks/CU.
// ---------------------------------------------------------------------------
__launch_bounds__(256)
__global__ void k_out(const _Float16* __restrict__ sReH,
                      const _Float16* __restrict__ sImH,
                      const _Float16* __restrict__ CreH,
                      const _Float16* __restrict__ CimNH,
                      const float* __restrict__ powRe,
                      const float* __restrict__ powIm,
                      const float* __restrict__ carRe,
                      const float* __restrict__ carIm,
                      const float* __restrict__ x,
                      const float* __restrict__ Dv,
                      float* __restrict__ y) {
    __shared__ __align__(16) _Float16 sA1[2][4096];   // 128 x 32
    __shared__ __align__(16) _Float16 sA2[2][4096];
    __shared__ __align__(16) _Float16 sCr[2][4096];
    __shared__ __align__(16) _Float16 sCi[2][4096];

    const int tid  = threadIdx.x;
    const int lane = tid & 63;
    const int wave = tid >> 6;
    const int wr   = wave >> 1;
    const int wc   = wave & 1;
    const int m0   = blockIdx.x * OBM;
    const int h0   = blockIdx.y * BN;
    const int chunk0 = m0 >> 6;

    // A/C staging map: row = tid>>1 (0..127), slots {2g2, 2g2+1}
    const int br = tid >> 1, g2 = tid & 1, bc = g2 * 16;
    const int fb = (br >> 1) & 3;
    const int bw0 = br * 32 + (((2 * g2)     ^ fb) * 8);
    const int bw1 = br * 32 + (((2 * g2 + 1) ^ fb) * 8);

    const int powRow   = br & 63;
    const int chunkIdx = chunk0 + (br >> 6);

    const int fRC   = lane & 15;
    const int rslot = (((lane >> 4) ^ (fRC >> 1)) & 3) * 8;

    fx4 acc[16];
#pragma unroll
    for (int i = 0; i < 16; ++i) acc[i] = (fx4)0.0f;

    half8 s1a, s1b, s2a, s2b, c0a, c0b, c1a, c1b;
    float4 pr0, pr1, pr2, pr3, pi0, pi1, pi2, pi3;
    float4 cr0, cr1, cr2, cr3, ci0, ci1, ci2, ci3;

#define LOAD_T(K0)                                                          \
    {                                                                       \
        size_t aOff = (size_t)(m0 + br) * NDIM + (K0) + bc;                 \
        s1a = *(const half8*)(sReH + aOff);  s1b = *(const half8*)(sReH + aOff + 8); \
        s2a = *(const half8*)(sImH + aOff);  s2b = *(const half8*)(sImH + aOff + 8); \
        size_t pOff = (size_t)powRow * NDIM + (K0) + bc;                    \
        pr0 = *(const float4*)(powRe + pOff);      pr1 = *(const float4*)(powRe + pOff + 4); \
        pr2 = *(const float4*)(powRe + pOff + 8);  pr3 = *(const float4*)(powRe + pOff + 12); \
        pi0 = *(const float4*)(powIm + pOff);      pi1 = *(const float4*)(powIm + pOff + 4); \
        pi2 = *(const float4*)(powIm + pOff + 8);  pi3 = *(const float4*)(powIm + pOff + 12); \
        size_t cOff = (size_t)chunkIdx * NDIM + (K0) + bc;                  \
        cr0 = *(const float4*)(carRe + cOff);      cr1 = *(const float4*)(carRe + cOff + 4); \
        cr2 = *(const float4*)(carRe + cOff + 8);  cr3 = *(const float4*)(carRe + cOff + 12); \
        ci0 = *(const float4*)(carIm + cOff);      ci1 = *(const float4*)(carIm + cOff + 4); \
        ci2 = *(const float4*)(carIm + cOff + 8);  ci3 = *(const float4*)(carIm + cOff + 12); \
        const _Float16* cp1 = CreH  + (size_t)(h0 + br) * NDIM + (K0) + bc; \
        const _Float16* cp2 = CimNH + (size_t)(h0 + br) * NDIM + (K0) + bc; \
        c0a = *(const half8*)cp1;  c0b = *(const half8*)(cp1 + 8);          \
        c1a = *(const half8*)cp2;  c1b = *(const half8*)(cp2 + 8);          \
    }
#define APPLY8(h1, h2, sA, sB, PR0, PR1, PI0, PI1, CR0, CR1, CI0, CI1)      \
    {                                                                       \
        float prA[8] = {PR0.x,PR0.y,PR0.z,PR0.w,PR1.x,PR1.y,PR1.z,PR1.w};   \
        float piA[8] = {PI0.x,PI0.y,PI0.z,PI0.w,PI1.x,PI1.y,PI1.z,PI1.w};   \
        float crA[8] = {CR0.x,CR0.y,CR0.z,CR0.w,CR1.x,CR1.y,CR1.z,CR1.w};   \
        float ciA[8] = {CI0.x,CI0.y,CI0.z,CI0.w,CI1.x,CI1.y,CI1.z,CI1.w};   \
        _Pragma("unroll")                                                   \
        for (int e = 0; e < 8; ++e) {                                       \
            float ur = fmaf(prA[e], crA[e], fmaf(-piA[e], ciA[e], (float)sA[e])); \
            float ui = fmaf(prA[e], ciA[e], fmaf( piA[e], crA[e], (float)sB[e])); \
            h1[e] = (_Float16)ur; h2[e] = (_Float16)ui;                     \
        }                                                                   \
    }
#define WRITE_T(PB)                                                         \
    {                                                                       \
        half8 h1, h2;                                                       \
        APPLY8(h1, h2, s1a, s2a, pr0, pr1, pi0, pi1, cr0, cr1, ci0, ci1);   \
        *(half8*)&sA1[PB][bw0] = h1;  *(half8*)&sA2[PB][bw0] = h2;          \
        APPLY8(h1, h2, s1b, s2b, pr2, pr3, pi2, pi3, cr2, cr3, ci2, ci3);   \
        *(half8*)&sA1[PB][bw1] = h1;  *(half8*)&sA2[PB][bw1] = h2;          \
        *(half8*)&sCr[PB][bw0] = c0a;  *(half8*)&sCr[PB][bw1] = c0b;        \
        *(half8*)&sCi[PB][bw0] = c1a;  *(half8*)&sCi[PB][bw1] = c1b;        \
    }

    LOAD_T(0);
    WRITE_T(0);
    __syncthreads();

    int p = 0;
    for (int k0 = 0; k0 < NDIM; k0 += BK) {
        const bool nx = (k0 + BK) < NDIM;
        if (nx) LOAD_T(k0 + BK);
        half8 af[4], bf[4];
#pragma unroll
        for (int sm = 0; sm < 4; ++sm)
            af[sm] = *(const half8*)&sA1[p][(wr * 64 + sm * 16 + fRC) * 32 + rslot];
#pragma unroll
        for (int sn = 0; sn < 4; ++sn)
            bf[sn] = *(const half8*)&sCr[p][(wc * 64 + sn * 16 + fRC) * 32 + rslot];
#pragma unroll
        for (int sm = 0; sm < 4; ++sm)
#pragma unroll
            for (int sn = 0; sn < 4; ++sn)
                acc[sm * 4 + sn] = __builtin_amdgcn_mfma_f32_16x16x32_f16(af[sm], bf[sn], acc[sm * 4 + sn], 0, 0, 0);
#pragma unroll
        for (int sm = 0; sm < 4; ++sm)
            af[sm] = *(const half8*)&sA2[p][(wr * 64 + sm * 16 + fRC) * 32 + rslot];
#pragma unroll
        for (int sn = 0; sn < 4; ++sn)
            bf[sn] = *(const half8*)&sCi[p][(wc * 64 + sn * 16 + fRC) * 32 + rslot];
#pragma unroll
        for (int sm = 0; sm < 4; ++sm)
#pragma unroll
            for (int sn = 0; sn < 4; ++sn)
                acc[sm * 4 + sn] = __builtin_amdgcn_mfma_f32_16x16x32_f16(af[sm], bf[sn], acc[sm * 4 + sn], 0, 0, 0);
        if (nx) WRITE_T(p ^ 1);
        __syncthreads();
        p ^= 1;
    }
#undef LOAD_T
#undef APPLY8
#undef WRITE_T

    float d[4];
#pragma unroll
    for (int sn = 0; sn < 4; ++sn) d[sn] = Dv[h0 + wc * 64 + sn * 16 + fRC];

    const int rBase = (lane >> 4) * 4;
#pragma unroll
    for (int sm = 0; sm < 4; ++sm)
#pragma unroll
        for (int sn = 0; sn < 4; ++sn) {
            int h = h0 + wc * 64 + sn * 16 + fRC;
#pragma unroll
            for (int reg = 0; reg < 4; ++reg) {
                int m = m0 + wr * 64 + sm * 16 + rBase + reg;
                size_t idx = (size_t)m * HDIM + h;
                y[idx] = fmaf(x[idx], d[sn], acc[sm * 4 + sn][reg]);
            }
        }
}

// ---------------------------------------------------------------------------
extern "C" void kernel_launch(void* const* d_in, const int* in_sizes, int n_in,
                              void* d_out, int out_size, void* d_ws, size_t ws_size,
                              hipStream_t stream) {
    const float* x      = (const float*)d_in[0];
    const float* B_re   = (const float*)d_in[1];
    const float* B_im   = (const float*)d_in[2];
    const float* C_re   = (const float*)d_in[3];
    const float* C_im   = (const float*)d_in[4];
    const float* nu_log = (const float*)d_in[5];
    const float* th_log = (const float*)d_in[6];
    const float* D      = (const float*)d_in[7];
    float* y = (float*)d_out;

    char* p = (char*)d_ws;
    _Float16* stReH = (_Float16*)p;  p += (size_t)MROWS * NDIM * 2;
    _Float16* stImH = (_Float16*)p;  p += (size_t)MROWS * NDIM * 2;
    _Float16* BreH  = (_Float16*)p;  p += (size_t)NDIM * HDIM * 2;
    _Float16* BimH  = (_Float16*)p;  p += (size_t)NDIM * HDIM * 2;
    _Float16* CreH  = (_Float16*)p;  p += (size_t)HDIM * NDIM * 2;
    _Float16* CimNH = (_Float16*)p;  p += (size_t)HDIM * NDIM * 2;
    float* lamRe = (float*)p;  p += NDIM * 4;
    float* lamIm = (float*)p;  p += NDIM * 4;
    float* powRe = (float*)p;  p += (size_t)CH * NDIM * 4;
    float* powIm = (float*)p;  p += (size_t)CH * NDIM * 4;
    float* finRe = (float*)p;  p += (size_t)B_SZ * NC * NDIM * 4;
    float* finIm = (float*)p;  p += (size_t)B_SZ * NC * NDIM * 4;
    float* carRe = (float*)p;  p += (size_t)B_SZ * NC * NDIM * 4;
    float* carIm = (float*)p;  p += (size_t)B_SZ * NC * NDIM * 4;

    k_prep<<<NDIM, 256, 0, stream>>>(B_re, B_im, C_re, C_im, nu_log, th_log,
                                     BreH, BimH, CreH, CimNH, lamRe, lamIm,
                                     powRe, powIm);

    dim3 gGemm(MROWS / BM, NDIM / BN);
    k_buscan<<<gGemm, 256, 0, stream>>>(x, BreH, BimH, lamRe, lamIm,
                                        stReH, stImH, finRe, finIm);

    k_carry<<<(B_SZ * NDIM) / 4, 256, 0, stream>>>(lamRe, lamIm, finRe, finIm,
                                                   carRe, carIm);

    dim3 gOut(MROWS / OBM, HDIM / BN);
    k_out<<<gOut, 256, 0, stream>>>(stReH, stImH, CreH, CimNH,
                                    powRe, powIm, carRe, carIm, x, D, y);
}

// Round 4
// 152.322 us; speedup vs baseline: 1.0208x; 1.0208x over previous
//
#include <hip/hip_runtime.h>
#include <hip/hip_bf16.h>
#include <math.h>

// Problem constants
#define B_SZ 8
#define LSEQ 4096
#define NDIM 256
#define HDIM 256
#define MROWS (B_SZ * LSEQ)     // 32768
#define CH 64                   // chunk length (== GEMM m-tile)
#define NC (LSEQ / CH)          // 64 chunks per batch

#define BM 64
#define BN 128                  // k_out n-tile
#define BK 32
#define SSTR 68                 // scan LDS col stride (halfs)

typedef _Float16 half8 __attribute__((ext_vector_type(8)));
typedef _Float16 half4 __attribute__((ext_vector_type(4)));
typedef float fx4 __attribute__((ext_vector_type(4)));

// ---------------------------------------------------------------------------
// k_prep: weights -> fp16 (gamma folded into B, Cim negated), Lambda re/im,
// and pow table P[i][n] = Lambda[n]^(i+1) for blocks < CH.  grid 256 x 256.
// ---------------------------------------------------------------------------
__global__ void k_prep(const float* __restrict__ Bre, const float* __restrict__ Bim,
                       const float* __restrict__ Cre, const float* __restrict__ Cim,
                       const float* __restrict__ nu_log, const float* __restrict__ th_log,
                       _Float16* __restrict__ BreH, _Float16* __restrict__ BimH,
                       _Float16* __restrict__ CreH, _Float16* __restrict__ CimNH,
                       float* __restrict__ lamRe, float* __restrict__ lamIm,
                       float* __restrict__ powRe, float* __restrict__ powIm) {
    int r = blockIdx.x;
    int t = threadIdx.x;
    float nu  = expf(nu_log[r]);
    float th  = expf(th_log[r]);
    float mod = expf(-nu);
    float g   = sqrtf(fmaxf(1.0f - mod * mod, 0.0f));
    if (t == 0) {
        lamRe[r] = mod * cosf(th);
        lamIm[r] = mod * sinf(th);
    }
    int i = r * 256 + t;
    BreH[i]  = (_Float16)(Bre[i] * g);
    BimH[i]  = (_Float16)(Bim[i] * g);
    CreH[i]  = (_Float16)Cre[i];
    CimNH[i] = (_Float16)(-Cim[i]);
    if (r < CH) {
        float nuN = expf(nu_log[t]);
        float thN = expf(th_log[t]);
        float k   = (float)(r + 1);
        float mo  = expf(-nuN * k);
        powRe[r * 256 + t] = mo * cosf(thN * k);
        powIm[r * 256 + t] = mo * sinf(thN * k);
    }
}

// ---------------------------------------------------------------------------
// k_buscan: fused  Bu = x @ B^T  GEMM  +  per-chunk local scan.
// NEW geometry: block = 64m x 256n (FULL n), 512 threads = 8 waves, wave
// tile 32m x 64n.  x is read once total (was twice).  LDS 73728 B -> 2
// blocks/CU = 16 waves/CU (4/SIMD), up from 12.
// Same verified swizzled-linear [row][32] LDS layout:
//   addr(row,col) = row*32 + ((col>>3) ^ ((row>>1)&3))*8 + (col&7)
// Fragment read slot: ((lane>>4) ^ ((lane&15)>>1)) & 3  (verified r2).
// per buffer p (po = p*18432): A at po (64x32), Br at po+2048 (256x32),
// Bi at po+10240.
// ---------------------------------------------------------------------------
__launch_bounds__(512, 4)
__global__ void k_buscan(const float* __restrict__ x,
                         const _Float16* __restrict__ BreH,
                         const _Float16* __restrict__ BimH,
                         const float* __restrict__ lamRe,
                         const float* __restrict__ lamIm,
                         _Float16* __restrict__ stReH,
                         _Float16* __restrict__ stImH,
                         float* __restrict__ finRe,
                         float* __restrict__ finIm) {
    // 73728 B union: GEMM dbuf (36864 halfs) / scan buffers (34816 halfs)
    __shared__ __align__(16) _Float16 smem[36864];

    const int tid  = threadIdx.x;
    const int lane = tid & 63;
    const int wave = tid >> 6;          // 0..7
    const int wr   = wave >> 2;         // 0..1  (m-half)
    const int wc   = wave & 3;          // 0..3  (n-quarter)
    const int m0   = blockIdx.x * BM;

    // A staging: thread t covers (row = t>>3, cols (t&7)*4 .. +3), half4
    const int ar = tid >> 3;
    const int ac = (tid & 7) * 4;
    const int aw = ar * 32 + ((((tid >> 1) & 3) ^ ((tid >> 4) & 3)) * 8) + (tid & 1) * 4;

    // B staging: row = t>>1 (0..255), k-groups {2g2, 2g2+1} (same map as r2)
    const int br = tid >> 1, g2 = tid & 1, bc = g2 * 16;
    const int fb = (br >> 1) & 3;
    const int bw0 = br * 32 + (((2 * g2)     ^ fb) * 8);
    const int bw1 = br * 32 + (((2 * g2 + 1) ^ fb) * 8);

    const int fRC   = lane & 15;
    const int rslot = (((lane >> 4) ^ (fRC >> 1)) & 3) * 8;

    fx4 accR[8], accI[8];
#pragma unroll
    for (int i = 0; i < 8; ++i) { accR[i] = (fx4)0.0f; accI[i] = (fx4)0.0f; }

    float4 xf0;
    half8 w0, w1, w2, w3;

#define LOAD_T(K0)                                                          \
    {                                                                       \
        const float* xp = x + (size_t)(m0 + ar) * HDIM + (K0) + ac;         \
        xf0 = *(const float4*)xp;                                           \
        const _Float16* bp1 = BreH + (size_t)br * HDIM + (K0) + bc;         \
        const _Float16* bp2 = BimH + (size_t)br * HDIM + (K0) + bc;         \
        w0 = *(const half8*)bp1;  w1 = *(const half8*)(bp1 + 8);            \
        w2 = *(const half8*)bp2;  w3 = *(const half8*)(bp2 + 8);            \
    }
#define WRITE_T(PO)                                                         \
    {                                                                       \
        half4 hv;                                                           \
        hv[0]=(_Float16)xf0.x; hv[1]=(_Float16)xf0.y;                       \
        hv[2]=(_Float16)xf0.z; hv[3]=(_Float16)xf0.w;                       \
        *(half4*)&smem[(PO) + aw] = hv;                                     \
        *(half8*)&smem[(PO) + 2048 + bw0]  = w0;                            \
        *(half8*)&smem[(PO) + 2048 + bw1]  = w1;                            \
        *(half8*)&smem[(PO) + 10240 + bw0] = w2;                            \
        *(half8*)&smem[(PO) + 10240 + bw1] = w3;                            \
    }

    LOAD_T(0);
    WRITE_T(0);
    __syncthreads();

    int p = 0;
    for (int k0 = 0; k0 < HDIM; k0 += BK) {
        const int po = p * 18432;
        const int qo = (p ^ 1) * 18432;
        const bool nx = (k0 + BK) < HDIM;
        if (nx) LOAD_T(k0 + BK);
        half8 af[2], bf[4];
#pragma unroll
        for (int sm = 0; sm < 2; ++sm)
            af[sm] = *(const half8*)&smem[po + (wr * 32 + sm * 16 + fRC) * 32 + rslot];
#pragma unroll
        for (int sn = 0; sn < 4; ++sn)
            bf[sn] = *(const half8*)&smem[po + 2048 + (wc * 64 + sn * 16 + fRC) * 32 + rslot];
#pragma unroll
        for (int sm = 0; sm < 2; ++sm)
#pragma unroll
            for (int sn = 0; sn < 4; ++sn)
                accR[sm * 4 + sn] = __builtin_amdgcn_mfma_f32_16x16x32_f16(af[sm], bf[sn], accR[sm * 4 + sn], 0, 0, 0);
#pragma unroll
        for (int sn = 0; sn < 4; ++sn)
            bf[sn] = *(const half8*)&smem[po + 10240 + (wc * 64 + sn * 16 + fRC) * 32 + rslot];
#pragma unroll
        for (int sm = 0; sm < 2; ++sm)
#pragma unroll
            for (int sn = 0; sn < 4; ++sn)
                accI[sm * 4 + sn] = __builtin_amdgcn_mfma_f32_16x16x32_f16(af[sm], bf[sn], accI[sm * 4 + sn], 0, 0, 0);
        if (nx) WRITE_T(qo);
        __syncthreads();
        p ^= 1;
    }
#undef LOAD_T
#undef WRITE_T

    _Float16* SRe = smem;               // [col][row], stride SSTR, 256 cols
    _Float16* SIm = smem + 17408;

    // Phase A: accumulators -> scan LDS (transposed), fp16
    const int rBase = (lane >> 4) * 4;
#pragma unroll
    for (int sm = 0; sm < 2; ++sm)
#pragma unroll
        for (int sn = 0; sn < 4; ++sn) {
            int col = wc * 64 + sn * 16 + fRC;
            int row = wr * 32 + sm * 16 + rBase;
            half4 h1, h2;
#pragma unroll
            for (int reg = 0; reg < 4; ++reg) {
                h1[reg] = (_Float16)accR[sm * 4 + sn][reg];
                h2[reg] = (_Float16)accI[sm * 4 + sn][reg];
            }
            *(half4*)&SRe[col * SSTR + row] = h1;
            *(half4*)&SIm[col * SSTR + row] = h2;
        }
    __syncthreads();

    // Phase B: per-column scan over 64 rows (fp32 state), threads 0..255
    if (tid < NDIM) {
        int col = tid;
        int n = col;
        float lr = lamRe[n], li = lamIm[n];
        _Float16* cR = &SRe[col * SSTR];
        _Float16* cI = &SIm[col * SSTR];
        float sr = 0.0f, si = 0.0f;
#pragma unroll 8
        for (int r = 0; r < CH; ++r) {
            float ur = (float)cR[r];
            float ui = (float)cI[r];
            float nr = fmaf(lr, sr, fmaf(-li, si, ur));
            float ni = fmaf(lr, si, fmaf(li, sr, ui));
            sr = nr; si = ni;
            cR[r] = (_Float16)sr;
            cI[r] = (_Float16)si;
        }
        int bb = blockIdx.x >> 6, cc = blockIdx.x & 63;
        size_t f = ((size_t)(bb * NC + cc)) * NDIM + n;
        finRe[f] = sr;
        finIm[f] = si;
    }
    __syncthreads();

    // Phase C: coalesced write of locally-scanned states to global (fp16).
    // row = t>>3, cb = (t&7)*8, cols cb + g*64.
    {
        int row = tid >> 3;
        int cb  = (tid & 7) * 8;
        size_t gbase = (size_t)(m0 + row) * NDIM + cb;
#pragma unroll
        for (int g = 0; g < 4; ++g) {
            half8 h1, h2;
#pragma unroll
            for (int e = 0; e < 8; ++e) {
                int col = cb + g * 64 + e;
                h1[e] = SRe[col * SSTR + row];
                h2[e] = SIm[col * SSTR + row];
            }
            *(half8*)(stReH + gbase + g * 64) = h1;
            *(half8*)(stImH + gbase + g * 64) = h2;
        }
    }
}

// ---------------------------------------------------------------------------
// k_carry: Kogge-Stone scan over the 64 chunk finals, chunks in lanes.
// (unchanged, verified round 2)
// ---------------------------------------------------------------------------
__launch_bounds__(256)
__global__ void k_carry(const float* __restrict__ lamRe,
                        const float* __restrict__ lamIm,
                        const float* __restrict__ finRe,
                        const float* __restrict__ finIm,
                        float* __restrict__ carRe,
                        float* __restrict__ carIm) {
    const int tid  = threadIdx.x;
    const int lane = tid & 63;
    const int wv   = tid >> 6;
    const int idx  = blockIdx.x * 4 + wv;
    const int b    = idx >> 8;
    const int n    = idx & 255;

    float plr = lamRe[n], pli = lamIm[n];
#pragma unroll
    for (int i = 0; i < 6; ++i) {
        float t = plr * plr - pli * pli;
        pli = 2.0f * plr * pli;
        plr = t;
    }

    size_t base = ((size_t)(b * NC + lane)) * NDIM + n;
    float vr = finRe[base];
    float vi = finIm[base];

#pragma unroll
    for (int d = 1; d < 64; d <<= 1) {
        float vpr = __shfl_up(vr, d);
        float vpi = __shfl_up(vi, d);
        float lpr = __shfl_up(plr, d);
        float lpi = __shfl_up(pli, d);
        if (lane >= d) {
            float nvr = fmaf(plr, vpr, fmaf(-pli, vpi, vr));
            float nvi = fmaf(plr, vpi, fmaf(pli, vpr, vi));
            vr = nvr; vi = nvi;
            float t = plr * lpr - pli * lpi;
            pli = fmaf(plr, lpi, pli * lpr);
            plr = t;
        }
    }

    float cr = __shfl_up(vr, 1);
    float ci = __shfl_up(vi, 1);
    if (lane == 0) { cr = 0.0f; ci = 0.0f; }
    carRe[base] = cr;
    carIm[base] = ci;
}

// ---------------------------------------------------------------------------
// k_out: y = s @ CreH^T + sIm @ CimNH^T + x*D, carry applied during A-staging:
// state[i] = local[i] + P[i]*carry  (P = Lambda^(i+1)).
// (reverted to exact verified round-2 form: BM=64, LDS 49152 B)
// ---------------------------------------------------------------------------
__launch_bounds__(256)
__global__ void k_out(const _Float16* __restrict__ sReH,
                      const _Float16* __restrict__ sImH,
                      const _Float16* __restrict__ CreH,
                      const _Float16* __restrict__ CimNH,
                      const float* __restrict__ powRe,
                      const float* __restrict__ powIm,
                      const float* __restrict__ carRe,
                      const float* __restrict__ carIm,
                      const float* __restrict__ x,
                      const float* __restrict__ Dv,
                      float* __restrict__ y) {
    __shared__ __align__(16) _Float16 sA1[2][2048];
    __shared__ __align__(16) _Float16 sA2[2][2048];
    __shared__ __align__(16) _Float16 sCr[2][4096];
    __shared__ __align__(16) _Float16 sCi[2][4096];

    const int tid  = threadIdx.x;
    const int lane = tid & 63;
    const int wave = tid >> 6;
    const int wr   = wave >> 1;
    const int wc   = wave & 1;
    const int m0   = blockIdx.x * BM;
    const int h0   = blockIdx.y * BN;
    const int chunk = m0 >> 6;

    const int ar = tid >> 2, ac = (tid & 3) * 8;
    const int aw = ar * 32 + (((tid & 3) ^ ((tid >> 3) & 3)) * 8);

    const int br = tid >> 1, g2 = tid & 1, bc = g2 * 16;
    const int fb = (br >> 1) & 3;
    const int bw0 = br * 32 + (((2 * g2)     ^ fb) * 8);
    const int bw1 = br * 32 + (((2 * g2 + 1) ^ fb) * 8);

    const int fRC   = lane & 15;
    const int rslot = (((lane >> 4) ^ (fRC >> 1)) & 3) * 8;

    fx4 acc[8];
#pragma unroll
    for (int i = 0; i < 8; ++i) acc[i] = (fx4)0.0f;

    half8 s1, s2, c0a, c0b, c1a, c1b;
    float4 pr0, pr1, pi0, pi1, cr0, cr1, ci0, ci1;

#define LOAD_T(K0)                                                          \
    {                                                                       \
        size_t aOff = (size_t)(m0 + ar) * NDIM + (K0) + ac;                 \
        s1 = *(const half8*)(sReH + aOff);                                  \
        s2 = *(const half8*)(sImH + aOff);                                  \
        size_t pOff = (size_t)ar * NDIM + (K0) + ac;                        \
        pr0 = *(const float4*)(powRe + pOff); pr1 = *(const float4*)(powRe + pOff + 4); \
        pi0 = *(const float4*)(powIm + pOff); pi1 = *(const float4*)(powIm + pOff + 4); \
        size_t cOff = (size_t)chunk * NDIM + (K0) + ac;                     \
        cr0 = *(const float4*)(carRe + cOff); cr1 = *(const float4*)(carRe + cOff + 4); \
        ci0 = *(const float4*)(carIm + cOff); ci1 = *(const float4*)(carIm + cOff + 4); \
        const _Float16* cp1 = CreH  + (size_t)(h0 + br) * NDIM + (K0) + bc; \
        const _Float16* cp2 = CimNH + (size_t)(h0 + br) * NDIM + (K0) + bc; \
        c0a = *(const half8*)cp1;  c0b = *(const half8*)(cp1 + 8);          \
        c1a = *(const half8*)cp2;  c1b = *(const half8*)(cp2 + 8);          \
    }
#define WRITE_T(PB)                                                         \
    {                                                                       \
        float prA[8] = {pr0.x,pr0.y,pr0.z,pr0.w,pr1.x,pr1.y,pr1.z,pr1.w};   \
        float piA[8] = {pi0.x,pi0.y,pi0.z,pi0.w,pi1.x,pi1.y,pi1.z,pi1.w};   \
        float crA[8] = {cr0.x,cr0.y,cr0.z,cr0.w,cr1.x,cr1.y,cr1.z,cr1.w};   \
        float ciA[8] = {ci0.x,ci0.y,ci0.z,ci0.w,ci1.x,ci1.y,ci1.z,ci1.w};   \
        half8 h1, h2;                                                       \
        _Pragma("unroll")                                                   \
        for (int e = 0; e < 8; ++e) {                                       \
            float ur = fmaf(prA[e], crA[e], fmaf(-piA[e], ciA[e], (float)s1[e])); \
            float ui = fmaf(prA[e], ciA[e], fmaf( piA[e], crA[e], (float)s2[e])); \
            h1[e] = (_Float16)ur; h2[e] = (_Float16)ui;                     \
        }                                                                   \
        *(half8*)&sA1[PB][aw] = h1;                                         \
        *(half8*)&sA2[PB][aw] = h2;                                         \
        *(half8*)&sCr[PB][bw0] = c0a;  *(half8*)&sCr[PB][bw1] = c0b;        \
        *(half8*)&sCi[PB][bw0] = c1a;  *(half8*)&sCi[PB][bw1] = c1b;        \
    }

    LOAD_T(0);
    WRITE_T(0);
    __syncthreads();

    int p = 0;
    for (int k0 = 0; k0 < NDIM; k0 += BK) {
        const bool nx = (k0 + BK) < NDIM;
        if (nx) LOAD_T(k0 + BK);
        half8 af[2], bf[4];
#pragma unroll
        for (int sm = 0; sm < 2; ++sm)
            af[sm] = *(const half8*)&sA1[p][(wr * 32 + sm * 16 + fRC) * 32 + rslot];
#pragma unroll
        for (int sn = 0; sn < 4; ++sn)
            bf[sn] = *(const half8*)&sCr[p][(wc * 64 + sn * 16 + fRC) * 32 + rslot];
#pragma unroll
        for (int sm = 0; sm < 2; ++sm)
#pragma unroll
            for (int sn = 0; sn < 4; ++sn)
                acc[sm * 4 + sn] = __builtin_amdgcn_mfma_f32_16x16x32_f16(af[sm], bf[sn], acc[sm * 4 + sn], 0, 0, 0);
#pragma unroll
        for (int sm = 0; sm < 2; ++sm)
            af[sm] = *(const half8*)&sA2[p][(wr * 32 + sm * 16 + fRC) * 32 + rslot];
#pragma unroll
        for (int sn = 0; sn < 4; ++sn)
            bf[sn] = *(const half8*)&sCi[p][(wc * 64 + sn * 16 + fRC) * 32 + rslot];
#pragma unroll
        for (int sm = 0; sm < 2; ++sm)
#pragma unroll
            for (int sn = 0; sn < 4; ++sn)
                acc[sm * 4 + sn] = __builtin_amdgcn_mfma_f32_16x16x32_f16(af[sm], bf[sn], acc[sm * 4 + sn], 0, 0, 0);
        if (nx) WRITE_T(p ^ 1);
        __syncthreads();
        p ^= 1;
    }
#undef LOAD_T
#undef WRITE_T

    float d[4];
#pragma unroll
    for (int sn = 0; sn < 4; ++sn) d[sn] = Dv[h0 + wc * 64 + sn * 16 + fRC];

    const int rBase = (lane >> 4) * 4;
#pragma unroll
    for (int sm = 0; sm < 2; ++sm)
#pragma unroll
        for (int sn = 0; sn < 4; ++sn) {
            int h = h0 + wc * 64 + sn * 16 + fRC;
#pragma unroll
            for (int reg = 0; reg < 4; ++reg) {
                int m = m0 + wr * 32 + sm * 16 + rBase + reg;
                size_t idx = (size_t)m * HDIM + h;
                y[idx] = fmaf(x[idx], d[sn], acc[sm * 4 + sn][reg]);
            }
        }
}

// ---------------------------------------------------------------------------
extern "C" void kernel_launch(void* const* d_in, const int* in_sizes, int n_in,
                              void* d_out, int out_size, void* d_ws, size_t ws_size,
                              hipStream_t stream) {
    const float* x      = (const float*)d_in[0];
    const float* B_re   = (const float*)d_in[1];
    const float* B_im   = (const float*)d_in[2];
    const float* C_re   = (const float*)d_in[3];
    const float* C_im   = (const float*)d_in[4];
    const float* nu_log = (const float*)d_in[5];
    const float* th_log = (const float*)d_in[6];
    const float* D      = (const float*)d_in[7];
    float* y = (float*)d_out;

    char* p = (char*)d_ws;
    _Float16* stReH = (_Float16*)p;  p += (size_t)MROWS * NDIM * 2;
    _Float16* stImH = (_Float16*)p;  p += (size_t)MROWS * NDIM * 2;
    _Float16* BreH  = (_Float16*)p;  p += (size_t)NDIM * HDIM * 2;
    _Float16* BimH  = (_Float16*)p;  p += (size_t)NDIM * HDIM * 2;
    _Float16* CreH  = (_Float16*)p;  p += (size_t)HDIM * NDIM * 2;
    _Float16* CimNH = (_Float16*)p;  p += (size_t)HDIM * NDIM * 2;
    float* lamRe = (float*)p;  p += NDIM * 4;
    float* lamIm = (float*)p;  p += NDIM * 4;
    float* powRe = (float*)p;  p += (size_t)CH * NDIM * 4;
    float* powIm = (float*)p;  p += (size_t)CH * NDIM * 4;
    float* finRe = (float*)p;  p += (size_t)B_SZ * NC * NDIM * 4;
    float* finIm = (float*)p;  p += (size_t)B_SZ * NC * NDIM * 4;
    float* carRe = (float*)p;  p += (size_t)B_SZ * NC * NDIM * 4;
    float* carIm = (float*)p;  p += (size_t)B_SZ * NC * NDIM * 4;

    k_prep<<<NDIM, 256, 0, stream>>>(B_re, B_im, C_re, C_im, nu_log, th_log,
                                     BreH, BimH, CreH, CimNH, lamRe, lamIm,
                                     powRe, powIm);

    k_buscan<<<MROWS / BM, 512, 0, stream>>>(x, BreH, BimH, lamRe, lamIm,
                                             stReH, stImH, finRe, finIm);

    k_carry<<<(B_SZ * NDIM) / 4, 256, 0, stream>>>(lamRe, lamIm, finRe, finIm,
                                                   carRe, carIm);

    dim3 gOut(MROWS / BM, HDIM / BN);
    k_out<<<gOut, 256, 0, stream>>>(stReH, stImH, CreH, CimNH,
                                    powRe, powIm, carRe, carIm, x, D, y);
}

// Round 8
// 149.977 us; speedup vs baseline: 1.0367x; 1.0156x over previous
//
#include <hip/hip_runtime.h>
#include <hip/hip_bf16.h>
#include <math.h>

// Problem constants
#define B_SZ 8
#define LSEQ 4096
#define NDIM 256
#define HDIM 256
#define MROWS (B_SZ * LSEQ)     // 32768
#define CH 64                   // chunk length (== GEMM m-tile)
#define NC (LSEQ / CH)          // 64 chunks per batch

#define BM 64
#define BN 128
#define BK 32
#define SSTR 68                 // scan LDS col stride (halfs)

typedef _Float16 half8 __attribute__((ext_vector_type(8)));
typedef _Float16 half4 __attribute__((ext_vector_type(4)));
typedef float fx4 __attribute__((ext_vector_type(4)));

// ---------------------------------------------------------------------------
// k_prep: weights -> fp16 (gamma folded into B, Cim negated), Lambda re/im,
// and pow table P[i][n] = Lambda[n]^(i+1) for blocks < CH.  grid 256 x 256.
// ---------------------------------------------------------------------------
__global__ void k_prep(const float* __restrict__ Bre, const float* __restrict__ Bim,
                       const float* __restrict__ Cre, const float* __restrict__ Cim,
                       const float* __restrict__ nu_log, const float* __restrict__ th_log,
                       _Float16* __restrict__ BreH, _Float16* __restrict__ BimH,
                       _Float16* __restrict__ CreH, _Float16* __restrict__ CimNH,
                       float* __restrict__ lamRe, float* __restrict__ lamIm,
                       float* __restrict__ powRe, float* __restrict__ powIm) {
    int r = blockIdx.x;
    int t = threadIdx.x;
    float nu  = expf(nu_log[r]);
    float th  = expf(th_log[r]);
    float mod = expf(-nu);
    float g   = sqrtf(fmaxf(1.0f - mod * mod, 0.0f));
    if (t == 0) {
        lamRe[r] = mod * cosf(th);
        lamIm[r] = mod * sinf(th);
    }
    int i = r * 256 + t;
    BreH[i]  = (_Float16)(Bre[i] * g);
    BimH[i]  = (_Float16)(Bim[i] * g);
    CreH[i]  = (_Float16)Cre[i];
    CimNH[i] = (_Float16)(-Cim[i]);
    if (r < CH) {
        float nuN = expf(nu_log[t]);
        float thN = expf(th_log[t]);
        float k   = (float)(r + 1);
        float mo  = expf(-nuN * k);
        powRe[r * 256 + t] = mo * cosf(thN * k);
        powIm[r * 256 + t] = mo * sinf(thN * k);
    }
}

// ---------------------------------------------------------------------------
// k_buscan: fused  Bu = x @ B^T  GEMM  +  per-chunk local scan.
// 64m x 128n block, 4 waves, BK=32 double-buffered LDS.
// LDS tiles are LINEAR [row][32] halfs with XOR slot swizzle:
//   slot s of row r holds k-group s ^ ((r>>1)&3)   (slot = 8 halfs = 16B)
// Staging is global->reg->ds_write; fragment reads use lane-constant slot
//   ((lane>>4) ^ ((lane&15)>>1)) & 3.
// LDS: dbuf 2 x (A 2048 + Br 4096 + Bi 4096) halfs = 40960 B.
// ---------------------------------------------------------------------------
__launch_bounds__(256)
__global__ void k_buscan(const float* __restrict__ x,
                         const _Float16* __restrict__ BreH,
                         const _Float16* __restrict__ BimH,
                         const float* __restrict__ lamRe,
                         const float* __restrict__ lamIm,
                         _Float16* __restrict__ stReH,
                         _Float16* __restrict__ stImH,
                         float* __restrict__ finRe,
                         float* __restrict__ finIm) {
    // 40960 B union: GEMM dbuf (20480 halfs) / scan buffers (17408 halfs)
    __shared__ __align__(16) _Float16 smem[20480];
    // per buffer p (po = p*10240): A at po, Br at po+2048, Bi at po+6144

    const int tid  = threadIdx.x;
    const int lane = tid & 63;
    const int wave = tid >> 6;
    const int wr   = wave >> 1;
    const int wc   = wave & 1;
    const int m0   = blockIdx.x * BM;
    const int n0   = blockIdx.y * BN;

    // A staging map: row ar, k-group (tid&3); swizzled slot write
    const int ar = tid >> 2, ac = (tid & 3) * 8;
    const int aw = ar * 32 + (((tid & 3) ^ ((tid >> 3) & 3)) * 8);

    // B staging map: row br, k-groups {2g2, 2g2+1}; swizzled slot writes
    const int br = tid >> 1, g2 = tid & 1, bc = g2 * 16;
    const int fb = (br >> 1) & 3;
    const int bw0 = br * 32 + (((2 * g2)     ^ fb) * 8);
    const int bw1 = br * 32 + (((2 * g2 + 1) ^ fb) * 8);

    const int fRC   = lane & 15;
    const int rslot = (((lane >> 4) ^ (fRC >> 1)) & 3) * 8; // fragment read slot

    fx4 accR[8], accI[8];
#pragma unroll
    for (int i = 0; i < 8; ++i) { accR[i] = (fx4)0.0f; accI[i] = (fx4)0.0f; }

    float4 xf0, xf1;
    half8 w0, w1, w2, w3;

#define LOAD_T(K0)                                                          \
    {                                                                       \
        const float* xp = x + (size_t)(m0 + ar) * HDIM + (K0) + ac;         \
        xf0 = *(const float4*)xp;                                           \
        xf1 = *(const float4*)(xp + 4);                                     \
        const _Float16* bp1 = BreH + (size_t)(n0 + br) * HDIM + (K0) + bc;  \
        const _Float16* bp2 = BimH + (size_t)(n0 + br) * HDIM + (K0) + bc;  \
        w0 = *(const half8*)bp1;  w1 = *(const half8*)(bp1 + 8);            \
        w2 = *(const half8*)bp2;  w3 = *(const half8*)(bp2 + 8);            \
    }
#define WRITE_T(PO)                                                         \
    {                                                                       \
        half8 hv;                                                           \
        hv[0]=(_Float16)xf0.x; hv[1]=(_Float16)xf0.y; hv[2]=(_Float16)xf0.z; hv[3]=(_Float16)xf0.w; \
        hv[4]=(_Float16)xf1.x; hv[5]=(_Float16)xf1.y; hv[6]=(_Float16)xf1.z; hv[7]=(_Float16)xf1.w; \
        *(half8*)&smem[(PO) + aw] = hv;                                     \
        *(half8*)&smem[(PO) + 2048 + bw0] = w0;                             \
        *(half8*)&smem[(PO) + 2048 + bw1] = w1;                             \
        *(half8*)&smem[(PO) + 6144 + bw0] = w2;                             \
        *(half8*)&smem[(PO) + 6144 + bw1] = w3;                             \
    }

    LOAD_T(0);
    WRITE_T(0);
    __syncthreads();

    int p = 0;
    for (int k0 = 0; k0 < HDIM; k0 += BK) {
        const int po = p * 10240;
        const int qo = (p ^ 1) * 10240;
        const bool nx = (k0 + BK) < HDIM;
        if (nx) LOAD_T(k0 + BK);
        half8 af[2], bf[4];
#pragma unroll
        for (int sm = 0; sm < 2; ++sm)
            af[sm] = *(const half8*)&smem[po + (wr * 32 + sm * 16 + fRC) * 32 + rslot];
#pragma unroll
        for (int sn = 0; sn < 4; ++sn)
            bf[sn] = *(const half8*)&smem[po + 2048 + (wc * 64 + sn * 16 + fRC) * 32 + rslot];
#pragma unroll
        for (int sm = 0; sm < 2; ++sm)
#pragma unroll
            for (int sn = 0; sn < 4; ++sn)
                accR[sm * 4 + sn] = __builtin_amdgcn_mfma_f32_16x16x32_f16(af[sm], bf[sn], accR[sm * 4 + sn], 0, 0, 0);
#pragma unroll
        for (int sn = 0; sn < 4; ++sn)
            bf[sn] = *(const half8*)&smem[po + 6144 + (wc * 64 + sn * 16 + fRC) * 32 + rslot];
#pragma unroll
        for (int sm = 0; sm < 2; ++sm)
#pragma unroll
            for (int sn = 0; sn < 4; ++sn)
                accI[sm * 4 + sn] = __builtin_amdgcn_mfma_f32_16x16x32_f16(af[sm], bf[sn], accI[sm * 4 + sn], 0, 0, 0);
        if (nx) WRITE_T(qo);
        __syncthreads();
        p ^= 1;
    }
#undef LOAD_T
#undef WRITE_T

    _Float16* SRe = smem;          // [col][row], stride SSTR
    _Float16* SIm = smem + 8704;

    // Phase A: accumulators -> scan LDS (transposed), fp16
    const int rBase = (lane >> 4) * 4;
#pragma unroll
    for (int sm = 0; sm < 2; ++sm)
#pragma unroll
        for (int sn = 0; sn < 4; ++sn) {
            int col = wc * 64 + sn * 16 + fRC;
            int row = wr * 32 + sm * 16 + rBase;
            half4 h1, h2;
#pragma unroll
            for (int reg = 0; reg < 4; ++reg) {
                h1[reg] = (_Float16)accR[sm * 4 + sn][reg];
                h2[reg] = (_Float16)accI[sm * 4 + sn][reg];
            }
            *(half4*)&SRe[col * SSTR + row] = h1;
            *(half4*)&SIm[col * SSTR + row] = h2;
        }
    __syncthreads();

    // Phase B: per-column scan over 64 rows (fp32 state), threads 0..127
    if (tid < BN) {
        int col = tid;
        int n = n0 + col;
        float lr = lamRe[n], li = lamIm[n];
        _Float16* cR = &SRe[col * SSTR];
        _Float16* cI = &SIm[col * SSTR];
        float sr = 0.0f, si = 0.0f;
#pragma unroll 8
        for (int r = 0; r < CH; ++r) {
            float ur = (float)cR[r];
            float ui = (float)cI[r];
            float nr = fmaf(lr, sr, fmaf(-li, si, ur));
            float ni = fmaf(lr, si, fmaf(li, sr, ui));
            sr = nr; si = ni;
            cR[r] = (_Float16)sr;
            cI[r] = (_Float16)si;
        }
        int bb = blockIdx.x >> 6, cc = blockIdx.x & 63;
        size_t f = ((size_t)(bb * NC + cc)) * NDIM + n;
        finRe[f] = sr;
        finIm[f] = si;
    }
    __syncthreads();

    // Phase C: coalesced write of locally-scanned states to global (fp16).
    {
        int row = tid >> 2;
        int cb  = (tid & 3) * 8;
        size_t gbase = (size_t)(m0 + row) * NDIM + n0 + cb;
#pragma unroll
        for (int g = 0; g < 4; ++g) {
            half8 h1, h2;
#pragma unroll
            for (int e = 0; e < 8; ++e) {
                int col = cb + g * 32 + e;
                h1[e] = SRe[col * SSTR + row];
                h2[e] = SIm[col * SSTR + row];
            }
            *(half8*)(stReH + gbase + g * 32) = h1;
            *(half8*)(stImH + gbase + g * 32) = h2;
        }
    }
}

// ---------------------------------------------------------------------------
// k_carry: Kogge-Stone scan over the 64 chunk finals, chunks in lanes.
// One wave per (batch, n) pair; 2048 pairs -> 512 blocks.
// ---------------------------------------------------------------------------
__launch_bounds__(256)
__global__ void k_carry(const float* __restrict__ lamRe,
                        const float* __restrict__ lamIm,
                        const float* __restrict__ finRe,
                        const float* __restrict__ finIm,
                        float* __restrict__ carRe,
                        float* __restrict__ carIm) {
    const int tid  = threadIdx.x;
    const int lane = tid & 63;
    const int wv   = tid >> 6;
    const int idx  = blockIdx.x * 4 + wv;   // 0..2047
    const int b    = idx >> 8;
    const int n    = idx & 255;

    // Lambda^64 via 6 squarings
    float plr = lamRe[n], pli = lamIm[n];
#pragma unroll
    for (int i = 0; i < 6; ++i) {
        float t = plr * plr - pli * pli;
        pli = 2.0f * plr * pli;
        plr = t;
    }

    size_t base = ((size_t)(b * NC + lane)) * NDIM + n;
    float vr = finRe[base];
    float vi = finIm[base];

    // inclusive Kogge-Stone over 64 lanes; element = (Lambda^64, fin)
#pragma unroll
    for (int d = 1; d < 64; d <<= 1) {
        float vpr = __shfl_up(vr, d);
        float vpi = __shfl_up(vi, d);
        float lpr = __shfl_up(plr, d);
        float lpi = __shfl_up(pli, d);
        if (lane >= d) {
            float nvr = fmaf(plr, vpr, fmaf(-pli, vpi, vr));
            float nvi = fmaf(plr, vpi, fmaf(pli, vpr, vi));
            vr = nvr; vi = nvi;
            float t = plr * lpr - pli * lpi;
            pli = fmaf(plr, lpi, pli * lpr);
            plr = t;
        }
    }

    // exclusive shift
    float cr = __shfl_up(vr, 1);
    float ci = __shfl_up(vi, 1);
    if (lane == 0) { cr = 0.0f; ci = 0.0f; }
    carRe[base] = cr;
    carIm[base] = ci;
}

// ---------------------------------------------------------------------------
// k_out: y = s @ CreH^T + sIm @ CimNH^T + x*D, carry applied during A-staging:
// state[i] = local[i] + P[i]*carry  (P = Lambda^(i+1)).
// Verified round-2 form: swizzled-linear LDS, reg-staged, LDS 49152 B.
// ---------------------------------------------------------------------------
__launch_bounds__(256)
__global__ void k_out(const _Float16* __restrict__ sReH,
                      const _Float16* __restrict__ sImH,
                      const _Float16* __restrict__ CreH,
                      const _Float16* __restrict__ CimNH,
                      const float* __restrict__ powRe,
                      const float* __restrict__ powIm,
                      const float* __restrict__ carRe,
                      const float* __restrict__ carIm,
                      const float* __restrict__ x,
                      const float* __restrict__ Dv,
                      float* __restrict__ y) {
    __shared__ __align__(16) _Float16 sA1[2][2048];
    __shared__ __align__(16) _Float16 sA2[2][2048];
    __shared__ __align__(16) _Float16 sCr[2][4096];
    __shared__ __align__(16) _Float16 sCi[2][4096];

    const int tid  = threadIdx.x;
    const int lane = tid & 63;
    const int wave = tid >> 6;
    const int wr   = wave >> 1;
    const int wc   = wave & 1;
    const int m0   = blockIdx.x * BM;
    const int h0   = blockIdx.y * BN;
    const int chunk = m0 >> 6;

    const int ar = tid >> 2, ac = (tid & 3) * 8;
    const int aw = ar * 32 + (((tid & 3) ^ ((tid >> 3) & 3)) * 8);

    const int br = tid >> 1, g2 = tid & 1, bc = g2 * 16;
    const int fb = (br >> 1) & 3;
    const int bw0 = br * 32 + (((2 * g2)     ^ fb) * 8);
    const int bw1 = br * 32 + (((2 * g2 + 1) ^ fb) * 8);

    const int fRC   = lane & 15;
    const int rslot = (((lane >> 4) ^ (fRC >> 1)) & 3) * 8;

    fx4 acc[8];
#pragma unroll
    for (int i = 0; i < 8; ++i) acc[i] = (fx4)0.0f;

    half8 s1, s2, c0a, c0b, c1a, c1b;
    float4 pr0, pr1, pi0, pi1, cr0, cr1, ci0, ci1;

#define LOAD_T(K0)                                                          \
    {                                                                       \
        size_t aOff = (size_t)(m0 + ar) * NDIM + (K0) + ac;                 \
        s1 = *(const half8*)(sReH + aOff);                                  \
        s2 = *(const half8*)(sImH + aOff);                                  \
        size_t pOff = (size_t)ar * NDIM + (K0) + ac;                        \
        pr0 = *(const float4*)(powRe + pOff); pr1 = *(const float4*)(powRe + pOff + 4); \
        pi0 = *(const float4*)(powIm + pOff); pi1 = *(const float4*)(powIm + pOff + 4); \
        size_t cOff = (size_t)chunk * NDIM + (K0) + ac;                     \
        cr0 = *(const float4*)(carRe + cOff); cr1 = *(const float4*)(carRe + cOff + 4); \
        ci0 = *(const float4*)(carIm + cOff); ci1 = *(const float4*)(carIm + cOff + 4); \
        const _Float16* cp1 = CreH  + (size_t)(h0 + br) * NDIM + (K0) + bc; \
        const _Float16* cp2 = CimNH + (size_t)(h0 + br) * NDIM + (K0) + bc; \
        c0a = *(const half8*)cp1;  c0b = *(const half8*)(cp1 + 8);          \
        c1a = *(const half8*)cp2;  c1b = *(const half8*)(cp2 + 8);          \
    }
#define WRITE_T(PB)                                                         \
    {                                                                       \
        float prA[8] = {pr0.x,pr0.y,pr0.z,pr0.w,pr1.x,pr1.y,pr1.z,pr1.w};   \
        float piA[8] = {pi0.x,pi0.y,pi0.z,pi0.w,pi1.x,pi1.y,pi1.z,pi1.w};   \
        float crA[8] = {cr0.x,cr0.y,cr0.z,cr0.w,cr1.x,cr1.y,cr1.z,cr1.w};   \
        float ciA[8] = {ci0.x,ci0.y,ci0.z,ci0.w,ci1.x,ci1.y,ci1.z,ci1.w};   \
        half8 h1, h2;                                                       \
        _Pragma("unroll")                                                   \
        for (int e = 0; e < 8; ++e) {                                       \
            float ur = fmaf(prA[e], crA[e], fmaf(-piA[e], ciA[e], (float)s1[e])); \
            float ui = fmaf(prA[e], ciA[e], fmaf( piA[e], crA[e], (float)s2[e])); \
            h1[e] = (_Float16)ur; h2[e] = (_Float16)ui;                     \
        }                                                                   \
        *(half8*)&sA1[PB][aw] = h1;                                         \
        *(half8*)&sA2[PB][aw] = h2;                                         \
        *(half8*)&sCr[PB][bw0] = c0a;  *(half8*)&sCr[PB][bw1] = c0b;        \
        *(half8*)&sCi[PB][bw0] = c1a;  *(half8*)&sCi[PB][bw1] = c1b;        \
    }

    LOAD_T(0);
    WRITE_T(0);
    __syncthreads();

    int p = 0;
    for (int k0 = 0; k0 < NDIM; k0 += BK) {
        const bool nx = (k0 + BK) < NDIM;
        if (nx) LOAD_T(k0 + BK);
        half8 af[2], bf[4];
#pragma unroll
        for (int sm = 0; sm < 2; ++sm)
            af[sm] = *(const half8*)&sA1[p][(wr * 32 + sm * 16 + fRC) * 32 + rslot];
#pragma unroll
        for (int sn = 0; sn < 4; ++sn)
            bf[sn] = *(const half8*)&sCr[p][(wc * 64 + sn * 16 + fRC) * 32 + rslot];
#pragma unroll
        for (int sm = 0; sm < 2; ++sm)
#pragma unroll
            for (int sn = 0; sn < 4; ++sn)
                acc[sm * 4 + sn] = __builtin_amdgcn_mfma_f32_16x16x32_f16(af[sm], bf[sn], acc[sm * 4 + sn], 0, 0, 0);
#pragma unroll
        for (int sm = 0; sm < 2; ++sm)
            af[sm] = *(const half8*)&sA2[p][(wr * 32 + sm * 16 + fRC) * 32 + rslot];
#pragma unroll
        for (int sn = 0; sn < 4; ++sn)
            bf[sn] = *(const half8*)&sCi[p][(wc * 64 + sn * 16 + fRC) * 32 + rslot];
#pragma unroll
        for (int sm = 0; sm < 2; ++sm)
#pragma unroll
            for (int sn = 0; sn < 4; ++sn)
                acc[sm * 4 + sn] = __builtin_amdgcn_mfma_f32_16x16x32_f16(af[sm], bf[sn], acc[sm * 4 + sn], 0, 0, 0);
        if (nx) WRITE_T(p ^ 1);
        __syncthreads();
        p ^= 1;
    }
#undef LOAD_T
#undef WRITE_T

    float d[4];
#pragma unroll
    for (int sn = 0; sn < 4; ++sn) d[sn] = Dv[h0 + wc * 64 + sn * 16 + fRC];

    const int rBase = (lane >> 4) * 4;
#pragma unroll
    for (int sm = 0; sm < 2; ++sm)
#pragma unroll
        for (int sn = 0; sn < 4; ++sn) {
            int h = h0 + wc * 64 + sn * 16 + fRC;
#pragma unroll
            for (int reg = 0; reg < 4; ++reg) {
                int m = m0 + wr * 32 + sm * 16 + rBase + reg;
                size_t idx = (size_t)m * HDIM + h;
                y[idx] = fmaf(x[idx], d[sn], acc[sm * 4 + sn][reg]);
            }
        }
}

// ---------------------------------------------------------------------------
extern "C" void kernel_launch(void* const* d_in, const int* in_sizes, int n_in,
                              void* d_out, int out_size, void* d_ws, size_t ws_size,
                              hipStream_t stream) {
    const float* x      = (const float*)d_in[0];
    const float* B_re   = (const float*)d_in[1];
    const float* B_im   = (const float*)d_in[2];
    const float* C_re   = (const float*)d_in[3];
    const float* C_im   = (const float*)d_in[4];
    const float* nu_log = (const float*)d_in[5];
    const float* th_log = (const float*)d_in[6];
    const float* D      = (const float*)d_in[7];
    float* y = (float*)d_out;

    char* p = (char*)d_ws;
    _Float16* stReH = (_Float16*)p;  p += (size_t)MROWS * NDIM * 2;
    _Float16* stImH = (_Float16*)p;  p += (size_t)MROWS * NDIM * 2;
    _Float16* BreH  = (_Float16*)p;  p += (size_t)NDIM * HDIM * 2;
    _Float16* BimH  = (_Float16*)p;  p += (size_t)NDIM * HDIM * 2;
    _Float16* CreH  = (_Float16*)p;  p += (size_t)HDIM * NDIM * 2;
    _Float16* CimNH = (_Float16*)p;  p += (size_t)HDIM * NDIM * 2;
    float* lamRe = (float*)p;  p += NDIM * 4;
    float* lamIm = (float*)p;  p += NDIM * 4;
    float* powRe = (float*)p;  p += (size_t)CH * NDIM * 4;
    float* powIm = (float*)p;  p += (size_t)CH * NDIM * 4;
    float* finRe = (float*)p;  p += (size_t)B_SZ * NC * NDIM * 4;
    float* finIm = (float*)p;  p += (size_t)B_SZ * NC * NDIM * 4;
    float* carRe = (float*)p;  p += (size_t)B_SZ * NC * NDIM * 4;
    float* carIm = (float*)p;  p += (size_t)B_SZ * NC * NDIM * 4;

    k_prep<<<NDIM, 256, 0, stream>>>(B_re, B_im, C_re, C_im, nu_log, th_log,
                                     BreH, BimH, CreH, CimNH, lamRe, lamIm,
                                     powRe, powIm);

    dim3 gGemm(MROWS / BM, NDIM / BN);
    k_buscan<<<gGemm, 256, 0, stream>>>(x, BreH, BimH, lamRe, lamIm,
                                        stReH, stImH, finRe, finIm);

    k_carry<<<(B_SZ * NDIM) / 4, 256, 0, stream>>>(lamRe, lamIm, finRe, finIm,
                                                   carRe, carIm);

    dim3 gOut(MROWS / BM, HDIM / BN);
    k_out<<<gOut, 256, 0, stream>>>(stReH, stImH, CreH, CimNH,
                                    powRe, powIm, carRe, carIm, x, D, y);
}